// Round 11
// baseline (663.961 us; speedup 1.0000x reference)
//
#include <hip/hip_runtime.h>
#include <hip/hip_bf16.h>

typedef __attribute__((ext_vector_type(8))) short bf16x8v;
typedef __attribute__((ext_vector_type(4))) float f32x4v;

#define DEV __device__ __forceinline__

constexpr int Bn = 8, Sn = 4096, En = 512, Hn = 512;
constexpr int Mn = Bn * Sn;          // 32768 rows
constexpr int NCc = 128, CHc = 32;   // scan: 128 chunks of 32
constexpr size_t SLOT = 33579008;    // = 8*4099*512*2 bytes (padded-conv buffer), 4096-aligned

// ---------- math helpers ----------
DEV float bfu(unsigned u){ union{unsigned v; float f;} c; c.v = u << 16; return c.f; }

DEV void gload16(const void* g, void* l){
  __builtin_amdgcn_global_load_lds((const __attribute__((address_space(1))) void*)g,
                                   (__attribute__((address_space(3))) void*)l, 16, 0, 0);
}

// linear-space gates: f' = (1+e^-i)/(2+e^-f+e^-i), i' = (1+e^-f)/(...), g = x>=0? x+.5 : sigmoid(x)
DEV void gate_lin(float f, float i, float hp, float& fp, float& ig){
  const float ef = __expf(-f);
  const float ei = __expf(-i);
  const float rd = 1.f / (2.f + ef + ei);
  fp = (1.f + ei) * rd;
  const float ipv = (1.f + ef) * rd;
  const float g = (hp >= 0.f) ? (hp + 0.5f) : (1.f / (1.f + __expf(-hp)));
  ig = ipv * g;
}

DEV float g_of(float x){ return (x >= 0.f) ? (x + 0.5f) : (1.f / (1.f + __expf(-x))); }

// ---------- bf16 MFMA GEMM, 256x128 tile, BK=32, 8 waves (4Mx2N), 512 thr ----------
// 2-blocks/CU x fine-interleave experiment: 3-buffer LDS (72 KB => 2 blocks/CU);
// r7's per-phase discipline kept exactly (ds_read || stage-unit || counted vmcnt
// || barrier || lgkm0+sched_barrier || setprio + MFMA cluster || barrier).
// 2 phases per BK=32 tile (m-halves, 8 MFMA each). Stage order per tile: A,A,B.
// vmcnt(3) once per tile at ph1: drains exactly tile t+1's 3 loads (needed next
// tile), keeps tile t+2's 3 in flight (2-tile latency cover). Tail: vmcnt(0).
// Mechanism under test: co-resident block fills this block's barrier/lgkm waits
// (m114 co-scheduling) -- the 1570cy/phase wait residue measured in r7/r9.
// C[M,N] = A(row-mapped)[M,K] * Bw[N,K]^T + bias
// A row base (elements) = rowg*aRS + (rowg>>12)*aBP   (handles padded conv layout)
// RES: 0 none, 1 add bf16 residual at res[r*rRS + (r>>12)*rBP + rOff + c]
template<int RES, bool RELU, bool OUTF32>
__global__ __launch_bounds__(512, 4)
void gemm_bf16(const __hip_bfloat16* __restrict__ A,
               const __hip_bfloat16* __restrict__ Bw,
               int N, int K, int aRS, int aBP,
               const float* __restrict__ bias,
               const __hip_bfloat16* __restrict__ res, int rRS, int rBP, int rOff,
               void* __restrict__ out)
{
  __shared__ __align__(16) __hip_bfloat16 Al[3][4][256][8];   // 48 KB
  __shared__ __align__(16) __hip_bfloat16 Bl[3][4][128][8];   // 24 KB
  const int tid  = threadIdx.x;
  const int lane = tid & 63;
  const int w    = tid >> 6;            // 0..7
  const int ntn  = N >> 7;
  // T1: XCD-aware bijective swizzle (all grids are multiples of 8)
  const int nwg = gridDim.x;
  int wg = blockIdx.x;
  if ((nwg & 7) == 0) wg = ((wg & 7) * (nwg >> 3)) + (wg >> 3);
  const int bm = wg / ntn, bn = wg % ntn;
  const int rowBase = bm << 8, colBase = bn << 7;
  const int wm = w >> 1, wn = w & 1;    // 4 x 2 wave grid; wave tile 64x64
  const int r0 = lane & 15, kc = lane >> 4;

  f32x4v acc[4][4];
  #pragma unroll
  for (int i=0;i<4;i++)
    #pragma unroll
    for (int j=0;j<4;j++)
      #pragma unroll
      for (int q=0;q<4;q++) acc[i][j][q] = 0.f;

  // staging: A unit (256 rows x 32 k) = 1024 x16B slots -> 2/thread;
  //          B unit (128 rows x 32 k) = 512 slots -> 1/thread
  const int sr   = tid & 255;
  const int ac40 = tid >> 8;            // 0..1
  const int ac41 = ac40 + 2;            // 2..3
  const int brow = tid & 127, bc4 = tid >> 7;   // bc4 0..3
  const int rg = rowBase + sr;
  const size_t aoff0 = (size_t)rg*aRS + (size_t)(rg>>12)*aBP + (ac40<<3);
  const size_t aoff1 = aoff0 + 16;
  const size_t boff  = (size_t)(colBase + brow)*K + (bc4<<3);

  auto stageA = [&](int buf, int t){
    const int ke = t << 5;
    gload16(A + aoff0 + ke, &Al[buf][ac40][sr][0]);
    gload16(A + aoff1 + ke, &Al[buf][ac41][sr][0]);
  };
  auto stageB = [&](int buf, int t){
    gload16(Bw + boff + (t<<5), &Bl[buf][bc4][brow][0]);
  };

  const int NT = K >> 5;                // 16 (K=512) or 64 (K=2048)

  // prologue: stage tiles 0 and 1; tile 0 must land (keep tile 1's 3 in flight)
  stageA(0,0); stageB(0,0); stageA(1,1); stageB(1,1);
  asm volatile("s_waitcnt vmcnt(3)" ::: "memory");
  __builtin_amdgcn_s_barrier();

  int cur = 0;
  for (int t=0; t<NT; t++){
    int nb = cur + 2; if (nb >= 3) nb -= 3;
    const bool pre = (t+2 < NT);
    bf16x8v bfv[4], af[2];
    // ---- phase 0: m-frags 0,1 ----
    #pragma unroll
    for (int ni=0;ni<4;ni++) bfv[ni] = *(const bf16x8v*)&Bl[cur][kc][(wn<<6)+(ni<<4)+r0][0];
    af[0] = *(const bf16x8v*)&Al[cur][kc][(wm<<6)+r0][0];
    af[1] = *(const bf16x8v*)&Al[cur][kc][(wm<<6)+16+r0][0];
    if (pre) stageA(nb, t+2);
    __builtin_amdgcn_s_barrier();
    asm volatile("s_waitcnt lgkmcnt(0)" ::: "memory");
    __builtin_amdgcn_sched_barrier(0);
    __builtin_amdgcn_s_setprio(1);
    #pragma unroll
    for (int m=0;m<2;m++)
      #pragma unroll
      for (int ni=0;ni<4;ni++)
        acc[m][ni] = __builtin_amdgcn_mfma_f32_16x16x32_bf16(af[m], bfv[ni], acc[m][ni], 0, 0, 0);
    __builtin_amdgcn_s_setprio(0);
    __builtin_amdgcn_s_barrier();
    // ---- phase 1: m-frags 2,3 ----
    af[0] = *(const bf16x8v*)&Al[cur][kc][(wm<<6)+32+r0][0];
    af[1] = *(const bf16x8v*)&Al[cur][kc][(wm<<6)+48+r0][0];
    if (pre) stageB(nb, t+2);
    if (pre) asm volatile("s_waitcnt vmcnt(3)" ::: "memory");
    else     asm volatile("s_waitcnt vmcnt(0)" ::: "memory");
    __builtin_amdgcn_s_barrier();
    asm volatile("s_waitcnt lgkmcnt(0)" ::: "memory");
    __builtin_amdgcn_sched_barrier(0);
    __builtin_amdgcn_s_setprio(1);
    #pragma unroll
    for (int m=0;m<2;m++)
      #pragma unroll
      for (int ni=0;ni<4;ni++)
        acc[2+m][ni] = __builtin_amdgcn_mfma_f32_16x16x32_bf16(af[m], bfv[ni], acc[2+m][ni], 0, 0, 0);
    __builtin_amdgcn_s_setprio(0);
    __builtin_amdgcn_s_barrier();
    cur = (cur + 1 == 3) ? 0 : cur + 1;
  }

  float* outF = (float*)out;
  __hip_bfloat16* outH = (__hip_bfloat16*)out;
  const int q = lane >> 4;
  float bia[4];
  #pragma unroll
  for (int ni=0;ni<4;ni++) bia[ni] = bias[colBase + (wn<<6) + (ni<<4) + r0];
  #pragma unroll
  for (int mi=0;mi<4;mi++){
    const int rb = rowBase + (wm<<6) + (mi<<4) + (q<<2);
    #pragma unroll
    for (int j=0;j<4;j++){
      const int r = rb + j;
      #pragma unroll
      for (int ni=0;ni<4;ni++){        // ni innermost: adjacent 32B chunks per row
        const int c = colBase + (wn<<6) + (ni<<4) + r0;
        float v = acc[mi][ni][j] + bia[ni];
        if constexpr (RES==1) v += __bfloat162float(res[(size_t)r*rRS + (size_t)(r>>12)*rBP + rOff + c]);
        if constexpr (RELU)   v = fmaxf(v, 0.f);
        if constexpr (OUTF32) outF[(size_t)r*N + c] = v;
        else                  outH[(size_t)r*N + c] = __float2bfloat16(v);
      }
    }
  }
}

// ---------- LayerNorm over last dim (512), one block per row, bf16 out ----------
template<bool INF32>
__global__ __launch_bounds__(256)
void ln_k(const void* __restrict__ xin, const float* __restrict__ g, const float* __restrict__ bta,
          __hip_bfloat16* __restrict__ outB, int bBP, int bOff)
{
  const int row = blockIdx.x, tid = threadIdx.x;
  float x0, x1;
  if constexpr (INF32){
    const float2 xv = ((const float2*)((const float*)xin + (size_t)row*En))[tid];
    x0 = xv.x; x1 = xv.y;
  } else {
    const unsigned u = ((const unsigned*)((const __hip_bfloat16*)xin + (size_t)row*En))[tid];
    x0 = bfu(u & 0xffffu); x1 = bfu(u >> 16);
  }
  float s = x0 + x1, sq = x0*x0 + x1*x1;
  #pragma unroll
  for (int off=32; off; off>>=1){ s += __shfl_down(s, off); sq += __shfl_down(sq, off); }
  __shared__ float red[8];
  const int w = tid >> 6, lane = tid & 63;
  if (lane == 0){ red[w] = s; red[4+w] = sq; }
  __syncthreads();
  s  = red[0]+red[1]+red[2]+red[3];
  sq = red[4]+red[5]+red[6]+red[7];
  const float mu   = s * (1.f/En);
  const float rstd = rsqrtf(sq * (1.f/En) - mu*mu + 1e-5f);
  const float2 gv = ((const float2*)g)[tid];
  const float2 bv = ((const float2*)bta)[tid];
  const float y0 = (x0 - mu)*rstd*gv.x + bv.x;
  const float y1 = (x1 - mu)*rstd*gv.y + bv.y;
  const size_t base = (size_t)row*En + (size_t)(row>>12)*bBP + bOff + tid*2;
  __hip_bfloat162 o; o.x = __float2bfloat16(y0); o.y = __float2bfloat16(y1);
  *(__hip_bfloat162*)(outB + base) = o;
}

// ---------- linear-space chunked scan over gates packed [row][1536] = f | i | h~ ----------
__global__ __launch_bounds__(256)
void scan_phaseA(const __hip_bfloat16* __restrict__ gi,
                 float* __restrict__ Aagg, float* __restrict__ Bagg)
{
  const int gid = blockIdx.x*256 + threadIdx.x;        // (b, c, hp)  hp in [0,256)
  const int hp = gid & 255, c = (gid >> 8) & 127, b = gid >> 15;
  size_t base = ((size_t)b*Sn + (size_t)c*CHc)*1536 + 2*hp;
  float A0 = 1.f, B0 = 0.f, A1 = 1.f, B1 = 0.f;
  for (int j=0;j<CHc;j++){
    const size_t idx = base + (size_t)j*1536;
    const unsigned uf = *(const unsigned*)(gi + idx);
    const unsigned ui = *(const unsigned*)(gi + idx + 512);
    const unsigned uh = *(const unsigned*)(gi + idx + 1024);
    float fp, ig;
    gate_lin(bfu(uf & 0xffffu), bfu(ui & 0xffffu), bfu(uh & 0xffffu), fp, ig);
    A0 *= fp; B0 = fp*B0 + ig;
    gate_lin(bfu(uf >> 16), bfu(ui >> 16), bfu(uh >> 16), fp, ig);
    A1 *= fp; B1 = fp*B1 + ig;
  }
  const int o = ((b*NCc + c) << 8) + hp;               // float2 index
  ((float2*)Aagg)[o] = make_float2(A0, A1);
  ((float2*)Bagg)[o] = make_float2(B0, B1);
}

__global__ __launch_bounds__(256)
void scan_phaseB(const float* __restrict__ h0, const float* __restrict__ Aagg,
                 const float* __restrict__ Bagg, float* __restrict__ Vst,
                 float* __restrict__ hlast)
{
  const int gid = blockIdx.x*256 + threadIdx.x;        // b*512 + h
  const int h = gid & 511, b = gid >> 9;
  float v = g_of(h0[gid]);
  for (int c=0;c<NCc;c++){
    const int idx = (b*NCc + c)*Hn + h;
    Vst[idx] = v;
    v = fmaf(Aagg[idx], v, Bagg[idx]);
  }
  hlast[gid] = v;
}

__global__ __launch_bounds__(256)
void scan_phaseC(const __hip_bfloat16* __restrict__ gi, const float* __restrict__ Vst,
                 __hip_bfloat16* __restrict__ hseq)
{
  const int gid = blockIdx.x*256 + threadIdx.x;        // (b, c, hp)
  const int hp = gid & 255, c = (gid >> 8) & 127, b = gid >> 15;
  size_t gbase = ((size_t)b*Sn + (size_t)c*CHc)*1536 + 2*hp;
  size_t obase = ((size_t)b*Sn + (size_t)c*CHc)*Hn  + 2*hp;
  const float2 v2 = ((const float2*)Vst)[((b*NCc + c) << 8) + hp];
  float v0 = v2.x, v1 = v2.y;
  for (int j=0;j<CHc;j++){
    const size_t idx = gbase + (size_t)j*1536;
    const unsigned uf = *(const unsigned*)(gi + idx);
    const unsigned ui = *(const unsigned*)(gi + idx + 512);
    const unsigned uh = *(const unsigned*)(gi + idx + 1024);
    float fp, ig;
    gate_lin(bfu(uf & 0xffffu), bfu(ui & 0xffffu), bfu(uh & 0xffffu), fp, ig);
    v0 = fmaf(fp, v0, ig);
    gate_lin(bfu(uf >> 16), bfu(ui >> 16), bfu(uh >> 16), fp, ig);
    v1 = fmaf(fp, v1, ig);
    __hip_bfloat162 o; o.x = __float2bfloat16(v0); o.y = __float2bfloat16(v1);
    *(__hip_bfloat162*)(hseq + obase + (size_t)j*Hn) = o;
  }
}

// ---------- small utility kernels ----------
__global__ void cvt_f32_bf16(const float* __restrict__ src, __hip_bfloat16* __restrict__ dst, int n){
  const int i = blockIdx.x*256 + threadIdx.x;
  if (i < n) dst[i] = __float2bfloat16(src[i]);
}

// conv_w [O=512][I=512][T=4] f32 -> wcv [O][T*512 + I] bf16
__global__ void conv_pack(const float* __restrict__ src, __hip_bfloat16* __restrict__ dst){
  const int d = blockIdx.x*256 + threadIdx.x;
  const int o = d >> 11, r = d & 2047, tap = r >> 9, i = r & 511;
  dst[d] = __float2bfloat16(src[(o*512 + i)*4 + tap]);
}

__global__ void pad_zero(__hip_bfloat16* __restrict__ padded){
  const int gid = blockIdx.x*256 + threadIdx.x;        // 8*3*512
  if (gid < Bn*3*En){
    const int b = gid / (3*En);
    const int j = gid % (3*En);
    const int which = j >> 9, e = j & 511;
    const int u = (which == 0) ? 0 : (4096 + which);   // rows 0, 4097, 4098
    padded[((size_t)b*(Sn+3) + u)*En + e] = __float2bfloat16(0.f);
  }
}

__global__ void pack_bias3(const float* __restrict__ a, const float* __restrict__ b,
                           const float* __restrict__ c, float* __restrict__ dst){
  const int i = blockIdx.x*256 + threadIdx.x;          // 1536
  if (i < 512)       dst[i] = a[i];
  else if (i < 1024) dst[i] = b[i-512];
  else if (i < 1536) dst[i] = c[i-1024];
}

extern "C" void kernel_launch(void* const* d_in, const int* in_sizes, int n_in,
                              void* d_out, int out_size, void* d_ws, size_t ws_size,
                              hipStream_t stream)
{
  const float* x     = (const float*)d_in[0];
  const float* h0    = (const float*)d_in[1];
  const float* lf_w  = (const float*)d_in[2];
  const float* lf_b  = (const float*)d_in[3];
  const float* li_w  = (const float*)d_in[4];
  const float* li_b  = (const float*)d_in[5];
  const float* lh_w  = (const float*)d_in[6];
  const float* lh_b  = (const float*)d_in[7];
  const float* out_w = (const float*)d_in[8];
  const float* out_b = (const float*)d_in[9];
  const float* conv_w= (const float*)d_in[10];
  const float* conv_b= (const float*)d_in[11];
  const float* ln_g  = (const float*)d_in[12];
  const float* ln_b  = (const float*)d_in[13];
  const float* w1    = (const float*)d_in[14];
  const float* b1    = (const float*)d_in[15];
  const float* w2    = (const float*)d_in[16];
  const float* b2    = (const float*)d_in[17];

  float* outx = (float*)d_out;
  float* outh = outx + (size_t)Mn*En;

  // ---- workspace layout (overlay plan) ----
  const size_t AGG = (size_t)Bn*NCc*Hn*4;              // 2 MB each
  const size_t NEED = 5*SLOT + 3*AGG + 8388608 + 6144;
  if (ws_size < NEED) return;

  char* W = (char*)d_ws;
  __hip_bfloat16* GI   = (__hip_bfloat16*)(W);
  __hip_bfloat16* X2   = (__hip_bfloat16*)(W);
  __hip_bfloat16* G1   = (__hip_bfloat16*)(W + SLOT);
  __hip_bfloat16* X3   = (__hip_bfloat16*)(W + 2*SLOT);
  __hip_bfloat16* HSEQ = (__hip_bfloat16*)(W + 3*SLOT);
  __hip_bfloat16* hmid = (__hip_bfloat16*)(W);
  __hip_bfloat16* XN1  = (__hip_bfloat16*)(W + 4*SLOT);   // later XN3
  float* Aagg = (float*)(W + 5*SLOT);
  float* Bagg = Aagg + (size_t)Bn*NCc*Hn;
  float* Vst  = Bagg + (size_t)Bn*NCc*Hn;
  __hip_bfloat16* wg3  = (__hip_bfloat16*)(Vst + (size_t)Bn*NCc*Hn);
  __hip_bfloat16* wout = wg3  + 1536*512;
  __hip_bfloat16* wcv  = wout + 512*512;
  __hip_bfloat16* wm1  = wcv  + 512*2048;
  __hip_bfloat16* wm2  = wm1  + 2048*512;
  float* bg3 = (float*)(wm2 + 512*2048);

  // weight prep
  cvt_f32_bf16<<<1024, 256, 0, stream>>>(lf_w, wg3,            512*512);
  cvt_f32_bf16<<<1024, 256, 0, stream>>>(li_w, wg3 +  512*512, 512*512);
  cvt_f32_bf16<<<1024, 256, 0, stream>>>(lh_w, wg3 + 1024*512, 512*512);
  cvt_f32_bf16<<<1024, 256, 0, stream>>>(out_w, wout, 512*512);
  cvt_f32_bf16<<<4096, 256, 0, stream>>>(w1, wm1, 2048*512);
  cvt_f32_bf16<<<4096, 256, 0, stream>>>(w2, wm2, 512*2048);
  conv_pack   <<<4096, 256, 0, stream>>>(conv_w, wcv);
  pack_bias3  <<<6,    256, 0, stream>>>(lf_b, li_b, lh_b, bg3);

  // LN1: x(f32) -> XN1 bf16
  ln_k<true><<<Mn, 256, 0, stream>>>(x, ln_g, ln_b, XN1, 0, 0);

  // fused gate GEMM: [Mn,512] x [1536,512]^T -> GI [Mn,1536]   (128 x 12 tiles)
  gemm_bf16<0,false,false><<<1536, 512, 0, stream>>>(XN1, wg3, 1536, 512, 512, 0, bg3, nullptr, 0,0,0, GI);

  // linear-space chunked scan -> HSEQ bf16, h_last f32
  scan_phaseA<<<1024, 256, 0, stream>>>(GI, Aagg, Bagg);
  scan_phaseB<<<16,   256, 0, stream>>>(h0, Aagg, Bagg, Vst, outh);
  scan_phaseC<<<1024, 256, 0, stream>>>(GI, Vst, HSEQ);

  // zero pad rows of G1 (after GI is dead — G1 overlays S1)
  pad_zero<<<48, 256, 0, stream>>>(G1);

  // out-proj + residual(XN1) -> X2 bf16   (128 x 4 tiles)
  gemm_bf16<1,false,false><<<512, 512, 0, stream>>>(HSEQ, wout, 512, 512, 512, 0, out_b, XN1, 512, 0, 0, X2);

  // LN2: X2 -> padded G1 (row t -> padded row t+1)
  ln_k<false><<<Mn, 256, 0, stream>>>(X2, ln_g, ln_b, G1, 3*En, En);

  // conv as K=2048 GEMM over padded rows + residual(xn2 from G1) -> X3 bf16
  gemm_bf16<1,false,false><<<512, 512, 0, stream>>>(G1, wcv, 512, 2048, 512, 3*En, conv_b, G1, 512, 3*En, En, X3);

  // LN3: X3 -> XN3 bf16 (reuses XN1 slot)
  ln_k<false><<<Mn, 256, 0, stream>>>(X3, ln_g, ln_b, XN1, 0, 0);

  // MLP: relu(XN3 @ w1^T) -> hmid (128 x 16 tiles);  hmid @ w2^T + XN3 -> outx (f32)
  gemm_bf16<0,true ,false><<<2048, 512, 0, stream>>>(XN1, wm1, 2048, 512, 512, 0, b1, nullptr, 0,0,0, hmid);
  gemm_bf16<1,false,true ><<<512,  512, 0, stream>>>(hmid, wm2, 512, 2048, 2048, 0, b2, XN1, 512, 0, 0, outx);
}

// Round 12
// 575.603 us; speedup vs baseline: 1.1535x; 1.1535x over previous
//
#include <hip/hip_runtime.h>
#include <hip/hip_bf16.h>

typedef __attribute__((ext_vector_type(8))) short bf16x8v;
typedef __attribute__((ext_vector_type(4))) float f32x4v;

#define DEV __device__ __forceinline__

constexpr int Bn = 8, Sn = 4096, En = 512, Hn = 512;
constexpr int Mn = Bn * Sn;          // 32768 rows
constexpr int NCc = 128, CHc = 32;   // scan: 128 chunks of 32
constexpr size_t SLOT = 33579008;    // = 8*4099*512*2 bytes (padded-conv buffer), 4096-aligned

// ---------- math helpers ----------
DEV float bfu(unsigned u){ union{unsigned v; float f;} c; c.v = u << 16; return c.f; }

DEV void gload16(const void* g, void* l){
  __builtin_amdgcn_global_load_lds((const __attribute__((address_space(1))) void*)g,
                                   (__attribute__((address_space(3))) void*)l, 16, 0, 0);
}

// linear-space gates: f' = (1+e^-i)/(2+e^-f+e^-i), i' = (1+e^-f)/(...), g = x>=0? x+.5 : sigmoid(x)
DEV void gate_lin(float f, float i, float hp, float& fp, float& ig){
  const float ef = __expf(-f);
  const float ei = __expf(-i);
  const float rd = 1.f / (2.f + ef + ei);
  fp = (1.f + ei) * rd;
  const float ipv = (1.f + ef) * rd;
  const float g = (hp >= 0.f) ? (hp + 0.5f) : (1.f / (1.f + __expf(-hp)));
  ig = ipv * g;
}

DEV float g_of(float x){ return (x >= 0.f) ? (x + 0.5f) : (1.f / (1.f + __expf(-x))); }

// ---------- bf16 MFMA GEMM, 256x256 tile, BK=64, 8 waves (2Mx4N), 512 thr ----------
// r9's 8-phase schedule + FRAGMENT DOUBLE-BUFFERING: phase p's MFMA runs on
// registers loaded during phase p-1, while phase p issues the ds_reads for
// phase p+1. This overlaps the two measured serial components of the 2180cy
// phase: LDS fragment drain (~577cy) and MFMA cluster (~620cy).
// Per phase: stage-unit -> [counted vmcnt] -> s_barrier -> issue ds_read(p+1)
// -> sched_barrier(0) -> setprio+MFMA(p) -> lgkmcnt(0).
// Hazards: p3's prefetch reads nxt-buf K0, drained by p3's vmcnt(4) BEFORE the
// barrier it follows; cross-wave WAR margin >=3 phase-bodies at <=1-body drift.
// C[M,N] = A(row-mapped)[M,K] * Bw[N,K]^T + bias
// RES: 0 none, 1 add bf16 residual at res[r*rRS + (r>>12)*rBP + rOff + c]
template<int RES, bool RELU, bool OUTF32>
__global__ __launch_bounds__(512, 1)
void gemm_bf16(const __hip_bfloat16* __restrict__ A,
               const __hip_bfloat16* __restrict__ Bw,
               int N, int K, int aRS, int aBP,
               const float* __restrict__ bias,
               const __hip_bfloat16* __restrict__ res, int rRS, int rBP, int rOff,
               void* __restrict__ out)
{
  __shared__ __align__(16) __hip_bfloat16 Al[2][8][256][8];   // 64 KB
  __shared__ __align__(16) __hip_bfloat16 Bl[2][8][256][8];   // 64 KB
  const int tid  = threadIdx.x;
  const int lane = tid & 63;
  const int w    = tid >> 6;            // 0..7
  const int ntn  = N >> 8;
  // T1: XCD-aware bijective swizzle (all grids are multiples of 8)
  const int nwg = gridDim.x;
  int wg = blockIdx.x;
  if ((nwg & 7) == 0) wg = ((wg & 7) * (nwg >> 3)) + (wg >> 3);
  const int bm = wg / ntn, bn = wg % ntn;
  const int rowBase = bm << 8, colBase = bn << 8;
  const int wm = w >> 2, wn = w & 3;    // 2 x 4 wave grid
  const int r0 = lane & 15, kc = lane >> 4;

  f32x4v acc[8][4];
  #pragma unroll
  for (int i=0;i<8;i++)
    #pragma unroll
    for (int j=0;j<4;j++)
      #pragma unroll
      for (int q=0;q<4;q++) acc[i][j][q] = 0.f;

  // staging: one K-half unit = 256 rows x 32 k = 1024 slots of 16B = 2/thread
  size_t aoff[2], boff[2];
  int srow[2], sc4[2];
  #pragma unroll
  for (int j=0;j<2;j++){
    const int slot = (j<<9) + tid;          // 0..2047
    const int c4 = slot >> 8, rw = slot & 255;
    srow[j] = rw; sc4[j] = c4;
    const int rowg = rowBase + rw;
    aoff[j] = (size_t)rowg*aRS + (size_t)(rowg>>12)*aBP + (c4<<3);
    boff[j] = (size_t)(colBase + rw)*K + (c4<<3);
  }

  // unit: 0=A-K0, 1=B-K0, 2=A-K1, 3=B-K1
  auto stage_unit = [&](int buf, int unit, int t){
    const int Kh = unit >> 1;
    const int ke = (t<<6) + (Kh<<5);
    if ((unit & 1) == 0){
      #pragma unroll
      for (int j=0;j<2;j++) gload16(A  + aoff[j] + ke, &Al[buf][(Kh<<2)+sc4[j]][srow[j]][0]);
    } else {
      #pragma unroll
      for (int j=0;j<2;j++) gload16(Bw + boff[j] + ke, &Bl[buf][(Kh<<2)+sc4[j]][srow[j]][0]);
    }
  };

  const int NT = K >> 6;           // 8 (K=512) or 32 (K=2048)

  // prologue: stage all 4 units of tile 0; K0 units must land
  stage_unit(0,0,0); stage_unit(0,1,0); stage_unit(0,2,0); stage_unit(0,3,0);
  asm volatile("s_waitcnt vmcnt(4)" ::: "memory");
  __builtin_amdgcn_s_barrier();

  // frag preload: a0 = A(h0,kk0), bv0 = B(kk0)
  bf16x8v a0[4], a1[4], bv0[4], bv1[4];
  #pragma unroll
  for (int ni=0;ni<4;ni++) bv0[ni] = *(const bf16x8v*)&Bl[0][kc][(wn<<6)+(ni<<4)+r0][0];
  #pragma unroll
  for (int m=0;m<4;m++)    a0[m]  = *(const bf16x8v*)&Al[0][kc][(wm<<7)+(m<<4)+r0][0];
  asm volatile("s_waitcnt lgkmcnt(0)" ::: "memory");

  for (int t=0; t<NT; t++){
    const int cur = t & 1, nxt = cur ^ 1;
    const bool pre = (t+1 < NT);
    // ---------- p0 (h0,kk0): MFMA(a0,bv0) -> acc[0..3]; prefetch a1 = A(h1,kk0)
    if (pre) stage_unit(nxt, 0, t+1);
    __builtin_amdgcn_s_barrier();
    #pragma unroll
    for (int m=0;m<4;m++) a1[m] = *(const bf16x8v*)&Al[cur][kc][(wm<<7)+((4+m)<<4)+r0][0];
    __builtin_amdgcn_sched_barrier(0);
    __builtin_amdgcn_s_setprio(1);
    #pragma unroll
    for (int m=0;m<4;m++)
      #pragma unroll
      for (int ni=0;ni<4;ni++)
        acc[m][ni] = __builtin_amdgcn_mfma_f32_16x16x32_bf16(a0[m], bv0[ni], acc[m][ni], 0, 0, 0);
    __builtin_amdgcn_s_setprio(0);
    asm volatile("s_waitcnt lgkmcnt(0)" ::: "memory");
    // ---------- p1 (h1,kk0): MFMA(a1,bv0) -> acc[4..7]; prefetch a0 = A(h0,kk1), bv1 = B(kk1)
    if (pre){ stage_unit(nxt, 1, t+1);
              asm volatile("s_waitcnt vmcnt(4)" ::: "memory"); }
    else      asm volatile("s_waitcnt vmcnt(0)" ::: "memory");
    __builtin_amdgcn_s_barrier();
    #pragma unroll
    for (int ni=0;ni<4;ni++) bv1[ni] = *(const bf16x8v*)&Bl[cur][4+kc][(wn<<6)+(ni<<4)+r0][0];
    #pragma unroll
    for (int m=0;m<4;m++)    a0[m]  = *(const bf16x8v*)&Al[cur][4+kc][(wm<<7)+(m<<4)+r0][0];
    __builtin_amdgcn_sched_barrier(0);
    __builtin_amdgcn_s_setprio(1);
    #pragma unroll
    for (int m=0;m<4;m++)
      #pragma unroll
      for (int ni=0;ni<4;ni++)
        acc[4+m][ni] = __builtin_amdgcn_mfma_f32_16x16x32_bf16(a1[m], bv0[ni], acc[4+m][ni], 0, 0, 0);
    __builtin_amdgcn_s_setprio(0);
    asm volatile("s_waitcnt lgkmcnt(0)" ::: "memory");
    // ---------- p2 (h0,kk1): MFMA(a0,bv1) -> acc[0..3]; prefetch a1 = A(h1,kk1)
    if (pre) stage_unit(nxt, 2, t+1);
    __builtin_amdgcn_s_barrier();
    #pragma unroll
    for (int m=0;m<4;m++) a1[m] = *(const bf16x8v*)&Al[cur][4+kc][(wm<<7)+((4+m)<<4)+r0][0];
    __builtin_amdgcn_sched_barrier(0);
    __builtin_amdgcn_s_setprio(1);
    #pragma unroll
    for (int m=0;m<4;m++)
      #pragma unroll
      for (int ni=0;ni<4;ni++)
        acc[m][ni] = __builtin_amdgcn_mfma_f32_16x16x32_bf16(a0[m], bv1[ni], acc[m][ni], 0, 0, 0);
    __builtin_amdgcn_s_setprio(0);
    asm volatile("s_waitcnt lgkmcnt(0)" ::: "memory");
    // ---------- p3 (h1,kk1): MFMA(a1,bv1) -> acc[4..7]; prefetch a0,bv0 from nxt
    if (pre){ stage_unit(nxt, 3, t+1);
              asm volatile("s_waitcnt vmcnt(4)" ::: "memory"); }
    else      asm volatile("s_waitcnt vmcnt(0)" ::: "memory");
    __builtin_amdgcn_s_barrier();
    if (pre){
      #pragma unroll
      for (int ni=0;ni<4;ni++) bv0[ni] = *(const bf16x8v*)&Bl[nxt][kc][(wn<<6)+(ni<<4)+r0][0];
      #pragma unroll
      for (int m=0;m<4;m++)    a0[m]  = *(const bf16x8v*)&Al[nxt][kc][(wm<<7)+(m<<4)+r0][0];
    }
    __builtin_amdgcn_sched_barrier(0);
    __builtin_amdgcn_s_setprio(1);
    #pragma unroll
    for (int m=0;m<4;m++)
      #pragma unroll
      for (int ni=0;ni<4;ni++)
        acc[4+m][ni] = __builtin_amdgcn_mfma_f32_16x16x32_bf16(a1[m], bv1[ni], acc[4+m][ni], 0, 0, 0);
    __builtin_amdgcn_s_setprio(0);
    asm volatile("s_waitcnt lgkmcnt(0)" ::: "memory");
  }

  float* outF = (float*)out;
  __hip_bfloat16* outH = (__hip_bfloat16*)out;
  const int q = lane >> 4;
  float bia[4];
  #pragma unroll
  for (int ni=0;ni<4;ni++) bia[ni] = bias[colBase + (wn<<6) + (ni<<4) + r0];
  #pragma unroll
  for (int mi=0;mi<8;mi++){
    const int rb = rowBase + (wm<<7) + (mi<<4) + (q<<2);
    #pragma unroll
    for (int j=0;j<4;j++){
      const int r = rb + j;
      #pragma unroll
      for (int ni=0;ni<4;ni++){        // ni innermost: adjacent 32B chunks per row
        const int c = colBase + (wn<<6) + (ni<<4) + r0;
        float v = acc[mi][ni][j] + bia[ni];
        if constexpr (RES==1) v += __bfloat162float(res[(size_t)r*rRS + (size_t)(r>>12)*rBP + rOff + c]);
        if constexpr (RELU)   v = fmaxf(v, 0.f);
        if constexpr (OUTF32) outF[(size_t)r*N + c] = v;
        else                  outH[(size_t)r*N + c] = __float2bfloat16(v);
      }
    }
  }
}

// ---------- LayerNorm over last dim (512), one block per row, bf16 out ----------
template<bool INF32>
__global__ __launch_bounds__(256)
void ln_k(const void* __restrict__ xin, const float* __restrict__ g, const float* __restrict__ bta,
          __hip_bfloat16* __restrict__ outB, int bBP, int bOff)
{
  const int row = blockIdx.x, tid = threadIdx.x;
  float x0, x1;
  if constexpr (INF32){
    const float2 xv = ((const float2*)((const float*)xin + (size_t)row*En))[tid];
    x0 = xv.x; x1 = xv.y;
  } else {
    const unsigned u = ((const unsigned*)((const __hip_bfloat16*)xin + (size_t)row*En))[tid];
    x0 = bfu(u & 0xffffu); x1 = bfu(u >> 16);
  }
  float s = x0 + x1, sq = x0*x0 + x1*x1;
  #pragma unroll
  for (int off=32; off; off>>=1){ s += __shfl_down(s, off); sq += __shfl_down(sq, off); }
  __shared__ float red[8];
  const int w = tid >> 6, lane = tid & 63;
  if (lane == 0){ red[w] = s; red[4+w] = sq; }
  __syncthreads();
  s  = red[0]+red[1]+red[2]+red[3];
  sq = red[4]+red[5]+red[6]+red[7];
  const float mu   = s * (1.f/En);
  const float rstd = rsqrtf(sq * (1.f/En) - mu*mu + 1e-5f);
  const float2 gv = ((const float2*)g)[tid];
  const float2 bv = ((const float2*)bta)[tid];
  const float y0 = (x0 - mu)*rstd*gv.x + bv.x;
  const float y1 = (x1 - mu)*rstd*gv.y + bv.y;
  const size_t base = (size_t)row*En + (size_t)(row>>12)*bBP + bOff + tid*2;
  __hip_bfloat162 o; o.x = __float2bfloat16(y0); o.y = __float2bfloat16(y1);
  *(__hip_bfloat162*)(outB + base) = o;
}

// ---------- linear-space chunked scan over gates packed [row][1536] = f | i | h~ ----------
__global__ __launch_bounds__(256)
void scan_phaseA(const __hip_bfloat16* __restrict__ gi,
                 float* __restrict__ Aagg, float* __restrict__ Bagg)
{
  const int gid = blockIdx.x*256 + threadIdx.x;        // (b, c, hp)  hp in [0,256)
  const int hp = gid & 255, c = (gid >> 8) & 127, b = gid >> 15;
  size_t base = ((size_t)b*Sn + (size_t)c*CHc)*1536 + 2*hp;
  float A0 = 1.f, B0 = 0.f, A1 = 1.f, B1 = 0.f;
  for (int j=0;j<CHc;j++){
    const size_t idx = base + (size_t)j*1536;
    const unsigned uf = *(const unsigned*)(gi + idx);
    const unsigned ui = *(const unsigned*)(gi + idx + 512);
    const unsigned uh = *(const unsigned*)(gi + idx + 1024);
    float fp, ig;
    gate_lin(bfu(uf & 0xffffu), bfu(ui & 0xffffu), bfu(uh & 0xffffu), fp, ig);
    A0 *= fp; B0 = fp*B0 + ig;
    gate_lin(bfu(uf >> 16), bfu(ui >> 16), bfu(uh >> 16), fp, ig);
    A1 *= fp; B1 = fp*B1 + ig;
  }
  const int o = ((b*NCc + c) << 8) + hp;               // float2 index
  ((float2*)Aagg)[o] = make_float2(A0, A1);
  ((float2*)Bagg)[o] = make_float2(B0, B1);
}

__global__ __launch_bounds__(256)
void scan_phaseB(const float* __restrict__ h0, const float* __restrict__ Aagg,
                 const float* __restrict__ Bagg, float* __restrict__ Vst,
                 float* __restrict__ hlast)
{
  const int gid = blockIdx.x*256 + threadIdx.x;        // b*512 + h
  const int h = gid & 511, b = gid >> 9;
  float v = g_of(h0[gid]);
  for (int c=0;c<NCc;c++){
    const int idx = (b*NCc + c)*Hn + h;
    Vst[idx] = v;
    v = fmaf(Aagg[idx], v, Bagg[idx]);
  }
  hlast[gid] = v;
}

__global__ __launch_bounds__(256)
void scan_phaseC(const __hip_bfloat16* __restrict__ gi, const float* __restrict__ Vst,
                 __hip_bfloat16* __restrict__ hseq)
{
  const int gid = blockIdx.x*256 + threadIdx.x;        // (b, c, hp)
  const int hp = gid & 255, c = (gid >> 8) & 127, b = gid >> 15;
  size_t gbase = ((size_t)b*Sn + (size_t)c*CHc)*1536 + 2*hp;
  size_t obase = ((size_t)b*Sn + (size_t)c*CHc)*Hn  + 2*hp;
  const float2 v2 = ((const float2*)Vst)[((b*NCc + c) << 8) + hp];
  float v0 = v2.x, v1 = v2.y;
  for (int j=0;j<CHc;j++){
    const size_t idx = gbase + (size_t)j*1536;
    const unsigned uf = *(const unsigned*)(gi + idx);
    const unsigned ui = *(const unsigned*)(gi + idx + 512);
    const unsigned uh = *(const unsigned*)(gi + idx + 1024);
    float fp, ig;
    gate_lin(bfu(uf & 0xffffu), bfu(ui & 0xffffu), bfu(uh & 0xffffu), fp, ig);
    v0 = fmaf(fp, v0, ig);
    gate_lin(bfu(uf >> 16), bfu(ui >> 16), bfu(uh >> 16), fp, ig);
    v1 = fmaf(fp, v1, ig);
    __hip_bfloat162 o; o.x = __float2bfloat16(v0); o.y = __float2bfloat16(v1);
    *(__hip_bfloat162*)(hseq + obase + (size_t)j*Hn) = o;
  }
}

// ---------- small utility kernels ----------
__global__ void cvt_f32_bf16(const float* __restrict__ src, __hip_bfloat16* __restrict__ dst, int n){
  const int i = blockIdx.x*256 + threadIdx.x;
  if (i < n) dst[i] = __float2bfloat16(src[i]);
}

// conv_w [O=512][I=512][T=4] f32 -> wcv [O][T*512 + I] bf16
__global__ void conv_pack(const float* __restrict__ src, __hip_bfloat16* __restrict__ dst){
  const int d = blockIdx.x*256 + threadIdx.x;
  const int o = d >> 11, r = d & 2047, tap = r >> 9, i = r & 511;
  dst[d] = __float2bfloat16(src[(o*512 + i)*4 + tap]);
}

__global__ void pad_zero(__hip_bfloat16* __restrict__ padded){
  const int gid = blockIdx.x*256 + threadIdx.x;        // 8*3*512
  if (gid < Bn*3*En){
    const int b = gid / (3*En);
    const int j = gid % (3*En);
    const int which = j >> 9, e = j & 511;
    const int u = (which == 0) ? 0 : (4096 + which);   // rows 0, 4097, 4098
    padded[((size_t)b*(Sn+3) + u)*En + e] = __float2bfloat16(0.f);
  }
}

__global__ void pack_bias3(const float* __restrict__ a, const float* __restrict__ b,
                           const float* __restrict__ c, float* __restrict__ dst){
  const int i = blockIdx.x*256 + threadIdx.x;          // 1536
  if (i < 512)       dst[i] = a[i];
  else if (i < 1024) dst[i] = b[i-512];
  else if (i < 1536) dst[i] = c[i-1024];
}

extern "C" void kernel_launch(void* const* d_in, const int* in_sizes, int n_in,
                              void* d_out, int out_size, void* d_ws, size_t ws_size,
                              hipStream_t stream)
{
  const float* x     = (const float*)d_in[0];
  const float* h0    = (const float*)d_in[1];
  const float* lf_w  = (const float*)d_in[2];
  const float* lf_b  = (const float*)d_in[3];
  const float* li_w  = (const float*)d_in[4];
  const float* li_b  = (const float*)d_in[5];
  const float* lh_w  = (const float*)d_in[6];
  const float* lh_b  = (const float*)d_in[7];
  const float* out_w = (const float*)d_in[8];
  const float* out_b = (const float*)d_in[9];
  const float* conv_w= (const float*)d_in[10];
  const float* conv_b= (const float*)d_in[11];
  const float* ln_g  = (const float*)d_in[12];
  const float* ln_b  = (const float*)d_in[13];
  const float* w1    = (const float*)d_in[14];
  const float* b1    = (const float*)d_in[15];
  const float* w2    = (const float*)d_in[16];
  const float* b2    = (const float*)d_in[17];

  float* outx = (float*)d_out;
  float* outh = outx + (size_t)Mn*En;

  // ---- workspace layout (overlay plan) ----
  const size_t AGG = (size_t)Bn*NCc*Hn*4;              // 2 MB each
  const size_t NEED = 5*SLOT + 3*AGG + 8388608 + 6144;
  if (ws_size < NEED) return;

  char* W = (char*)d_ws;
  __hip_bfloat16* GI   = (__hip_bfloat16*)(W);
  __hip_bfloat16* X2   = (__hip_bfloat16*)(W);
  __hip_bfloat16* G1   = (__hip_bfloat16*)(W + SLOT);
  __hip_bfloat16* X3   = (__hip_bfloat16*)(W + 2*SLOT);
  __hip_bfloat16* HSEQ = (__hip_bfloat16*)(W + 3*SLOT);
  __hip_bfloat16* hmid = (__hip_bfloat16*)(W);
  __hip_bfloat16* XN1  = (__hip_bfloat16*)(W + 4*SLOT);   // later XN3
  float* Aagg = (float*)(W + 5*SLOT);
  float* Bagg = Aagg + (size_t)Bn*NCc*Hn;
  float* Vst  = Bagg + (size_t)Bn*NCc*Hn;
  __hip_bfloat16* wg3  = (__hip_bfloat16*)(Vst + (size_t)Bn*NCc*Hn);
  __hip_bfloat16* wout = wg3  + 1536*512;
  __hip_bfloat16* wcv  = wout + 512*512;
  __hip_bfloat16* wm1  = wcv  + 512*2048;
  __hip_bfloat16* wm2  = wm1  + 2048*512;
  float* bg3 = (float*)(wm2 + 512*2048);

  // weight prep
  cvt_f32_bf16<<<1024, 256, 0, stream>>>(lf_w, wg3,            512*512);
  cvt_f32_bf16<<<1024, 256, 0, stream>>>(li_w, wg3 +  512*512, 512*512);
  cvt_f32_bf16<<<1024, 256, 0, stream>>>(lh_w, wg3 + 1024*512, 512*512);
  cvt_f32_bf16<<<1024, 256, 0, stream>>>(out_w, wout, 512*512);
  cvt_f32_bf16<<<4096, 256, 0, stream>>>(w1, wm1, 2048*512);
  cvt_f32_bf16<<<4096, 256, 0, stream>>>(w2, wm2, 512*2048);
  conv_pack   <<<4096, 256, 0, stream>>>(conv_w, wcv);
  pack_bias3  <<<6,    256, 0, stream>>>(lf_b, li_b, lh_b, bg3);

  // LN1: x(f32) -> XN1 bf16
  ln_k<true><<<Mn, 256, 0, stream>>>(x, ln_g, ln_b, XN1, 0, 0);

  // fused gate GEMM: [Mn,512] x [1536,512]^T -> GI [Mn,1536]   (128 x 6 tiles)
  gemm_bf16<0,false,false><<<768, 512, 0, stream>>>(XN1, wg3, 1536, 512, 512, 0, bg3, nullptr, 0,0,0, GI);

  // linear-space chunked scan -> HSEQ bf16, h_last f32
  scan_phaseA<<<1024, 256, 0, stream>>>(GI, Aagg, Bagg);
  scan_phaseB<<<16,   256, 0, stream>>>(h0, Aagg, Bagg, Vst, outh);
  scan_phaseC<<<1024, 256, 0, stream>>>(GI, Vst, HSEQ);

  // zero pad rows of G1 (after GI is dead — G1 overlays S1)
  pad_zero<<<48, 256, 0, stream>>>(G1);

  // out-proj + residual(XN1) -> X2 bf16   (128 x 2 tiles)
  gemm_bf16<1,false,false><<<256, 512, 0, stream>>>(HSEQ, wout, 512, 512, 512, 0, out_b, XN1, 512, 0, 0, X2);

  // LN2: X2 -> padded G1 (row t -> padded row t+1)
  ln_k<false><<<Mn, 256, 0, stream>>>(X2, ln_g, ln_b, G1, 3*En, En);

  // conv as K=2048 GEMM over padded rows + residual(xn2 from G1) -> X3 bf16
  gemm_bf16<1,false,false><<<256, 512, 0, stream>>>(G1, wcv, 512, 2048, 512, 3*En, conv_b, G1, 512, 3*En, En, X3);

  // LN3: X3 -> XN3 bf16 (reuses XN1 slot)
  ln_k<false><<<Mn, 256, 0, stream>>>(X3, ln_g, ln_b, XN1, 0, 0);

  // MLP: relu(XN3 @ w1^T) -> hmid (128 x 8 tiles);  hmid @ w2^T + XN3 -> outx (f32)
  gemm_bf16<0,true ,false><<<1024, 512, 0, stream>>>(XN1, wm1, 2048, 512, 512, 0, b1, nullptr, 0,0,0, hmid);
  gemm_bf16<1,false,true ><<<256,  512, 0, stream>>>(hmid, wm2, 512, 2048, 2048, 0, b2, XN1, 512, 0, 0, outx);
}

// Round 13
// 571.479 us; speedup vs baseline: 1.1618x; 1.0072x over previous
//
#include <hip/hip_runtime.h>
#include <hip/hip_bf16.h>

typedef __attribute__((ext_vector_type(8))) short bf16x8v;
typedef __attribute__((ext_vector_type(4))) float f32x4v;

#define DEV __device__ __forceinline__

constexpr int Bn = 8, Sn = 4096, En = 512, Hn = 512;
constexpr int Mn = Bn * Sn;          // 32768 rows
constexpr int NCc = 128, CHc = 32;   // scan: 128 chunks of 32
constexpr size_t SLOT = 33579008;    // = 8*4099*512*2 bytes (padded-conv buffer), 4096-aligned

// ---------- math helpers ----------
DEV float bfu(unsigned u){ union{unsigned v; float f;} c; c.v = u << 16; return c.f; }

DEV void gload16(const void* g, void* l){
  __builtin_amdgcn_global_load_lds((const __attribute__((address_space(1))) void*)g,
                                   (__attribute__((address_space(3))) void*)l, 16, 0, 0);
}

// linear-space gates: f' = (1+e^-i)/(2+e^-f+e^-i), i' = (1+e^-f)/(...), g = x>=0? x+.5 : sigmoid(x)
DEV void gate_lin(float f, float i, float hp, float& fp, float& ig){
  const float ef = __expf(-f);
  const float ei = __expf(-i);
  const float rd = 1.f / (2.f + ef + ei);
  fp = (1.f + ei) * rd;
  const float ipv = (1.f + ef) * rd;
  const float g = (hp >= 0.f) ? (hp + 0.5f) : (1.f / (1.f + __expf(-hp)));
  ig = ipv * g;
}

DEV float g_of(float x){ return (x >= 0.f) ? (x + 0.5f) : (1.f / (1.f + __expf(-x))); }

// ---------- bf16 MFMA GEMM, 256x256 tile, BK=64, 8 waves (2Mx4N), 512 thr ----------
// r9's 8-phase schedule MINUS the per-phase lgkmcnt(0)+"memory" asm and
// sched_barrier(0). Those 12 fences/K-tile forced the compiler to re-materialize
// every address after each phase (measured: 420cy/phase VALU where ~70 is needed)
// and froze its scheduler. The compiler's own fine-grained lgkmcnt before each
// MFMA (m97-verified) handles read->use ordering.
// Correctness audit without the explicit lgkm fences:
//  - RAW (stage -> next-tile read): the 2 memory-clobbered vmcnt asms per tile
//    are full compiler memory fences; reads of buffer `nxt` (next iteration)
//    cannot hoist above p3's vmcnt asm, and hardware vmcnt(4) guarantees the
//    staged data landed.
//  - WAR (read -> restage of same buffer, 2 tiles later): each wave's ds_reads
//    retire before its own phase MFMAs issue (hw lgkm tracking); 8 barriers
//    separate tile t's reads from tile t+2's stores. Safe with margin.
//  - vmcnt counting is positional: gloads cannot cross the memory-clobbered
//    vmcnt asms, so outstanding-count at each fence is unchanged.
// C[M,N] = A(row-mapped)[M,K] * Bw[N,K]^T + bias
// RES: 0 none, 1 add bf16 residual at res[r*rRS + (r>>12)*rBP + rOff + c]
template<int RES, bool RELU, bool OUTF32>
__global__ __launch_bounds__(512, 1)
void gemm_bf16(const __hip_bfloat16* __restrict__ A,
               const __hip_bfloat16* __restrict__ Bw,
               int N, int K, int aRS, int aBP,
               const float* __restrict__ bias,
               const __hip_bfloat16* __restrict__ res, int rRS, int rBP, int rOff,
               void* __restrict__ out)
{
  // chunked layout [k-chunk 0..7][row][8] — conflict-free ds_read_b128 pattern
  __shared__ __align__(16) __hip_bfloat16 Al[2][8][256][8];   // 64 KB
  __shared__ __align__(16) __hip_bfloat16 Bl[2][8][256][8];   // 64 KB
  const int tid  = threadIdx.x;
  const int lane = tid & 63;
  const int w    = tid >> 6;            // 0..7
  const int ntn  = N >> 8;
  // T1: XCD-aware bijective swizzle (all grids are multiples of 8)
  const int nwg = gridDim.x;
  int wg = blockIdx.x;
  if ((nwg & 7) == 0) wg = ((wg & 7) * (nwg >> 3)) + (wg >> 3);
  const int bm = wg / ntn, bn = wg % ntn;
  const int rowBase = bm << 8, colBase = bn << 8;
  const int wm = w >> 2, wn = w & 3;    // 2 x 4 wave grid
  const int r0 = lane & 15, kc = lane >> 4;

  f32x4v acc[8][4];
  #pragma unroll
  for (int i=0;i<8;i++)
    #pragma unroll
    for (int j=0;j<4;j++)
      #pragma unroll
      for (int q=0;q<4;q++) acc[i][j][q] = 0.f;

  // staging: one K-half unit = 256 rows x 32 k = 1024 slots of 16B = 2/thread
  size_t aoff[2], boff[2];
  int srow[2], sc4[2];
  #pragma unroll
  for (int j=0;j<2;j++){
    const int slot = (j<<9) + tid;          // 0..1023
    const int c4 = slot >> 8, rw = slot & 255;
    srow[j] = rw; sc4[j] = c4;
    const int rowg = rowBase + rw;
    aoff[j] = (size_t)rowg*aRS + (size_t)(rowg>>12)*aBP + (c4<<3);
    boff[j] = (size_t)(colBase + rw)*K + (c4<<3);
  }

  // unit: 0=A-K0, 1=B-K0, 2=A-K1, 3=B-K1  (issue order matters for vmcnt math)
  auto stage_unit = [&](int buf, int unit, int t){
    const int Kh = unit >> 1;
    const int ke = (t<<6) + (Kh<<5);
    if ((unit & 1) == 0){
      #pragma unroll
      for (int j=0;j<2;j++) gload16(A  + aoff[j] + ke, &Al[buf][(Kh<<2)+sc4[j]][srow[j]][0]);
    } else {
      #pragma unroll
      for (int j=0;j<2;j++) gload16(Bw + boff[j] + ke, &Bl[buf][(Kh<<2)+sc4[j]][srow[j]][0]);
    }
  };

  const int NT = K >> 6;           // 8 (K=512) or 32 (K=2048)

  // prologue: stage all 4 units of tile 0; first 2 units must land
  stage_unit(0,0,0); stage_unit(0,1,0); stage_unit(0,2,0); stage_unit(0,3,0);
  asm volatile("s_waitcnt vmcnt(4)" ::: "memory");
  __builtin_amdgcn_s_barrier();

  bf16x8v bfv[4];
  for (int t=0; t<NT; t++){
    const int cur = t & 1, nxt = cur ^ 1;
    const bool pre = (t+1 < NT);
    #pragma unroll
    for (int ph=0; ph<4; ph++){
      const int h = ph & 1, kk = ph >> 1;
      const int ch = (kk<<2) + kc;
      // ds-read this phase's fragments (compiler inserts fine-grained lgkmcnt)
      bf16x8v af[4];
      if (h == 0){
        #pragma unroll
        for (int ni=0;ni<4;ni++) bfv[ni] = *(const bf16x8v*)&Bl[cur][ch][(wn<<6)+(ni<<4)+r0][0];
      }
      #pragma unroll
      for (int m=0;m<4;m++) af[m] = *(const bf16x8v*)&Al[cur][ch][(wm<<7)+(((h<<2)+m)<<4)+r0][0];
      // stage one unit of tile t+1
      if (pre) stage_unit(nxt, ph, t+1);
      // counted waits: protect staged data of LATER phases (never 0 mid-loop)
      if (ph == 1 || ph == 3){
        if (pre) asm volatile("s_waitcnt vmcnt(4)" ::: "memory");
        else     asm volatile("s_waitcnt vmcnt(0)" ::: "memory");
      }
      __builtin_amdgcn_s_barrier();
      __builtin_amdgcn_s_setprio(1);
      #pragma unroll
      for (int m=0;m<4;m++)
        #pragma unroll
        for (int ni=0;ni<4;ni++)
          acc[(h<<2)+m][ni] = __builtin_amdgcn_mfma_f32_16x16x32_bf16(af[m], bfv[ni], acc[(h<<2)+m][ni], 0, 0, 0);
      __builtin_amdgcn_s_setprio(0);
      __builtin_amdgcn_s_barrier();
    }
  }

  float* outF = (float*)out;
  __hip_bfloat16* outH = (__hip_bfloat16*)out;
  const int q = lane >> 4;
  float bia[4];
  #pragma unroll
  for (int ni=0;ni<4;ni++) bia[ni] = bias[colBase + (wn<<6) + (ni<<4) + r0];
  #pragma unroll
  for (int mi=0;mi<8;mi++){
    const int rb = rowBase + (wm<<7) + (mi<<4) + (q<<2);
    #pragma unroll
    for (int j=0;j<4;j++){
      const int r = rb + j;
      #pragma unroll
      for (int ni=0;ni<4;ni++){        // ni innermost: adjacent 32B chunks per row
        const int c = colBase + (wn<<6) + (ni<<4) + r0;
        float v = acc[mi][ni][j] + bia[ni];
        if constexpr (RES==1) v += __bfloat162float(res[(size_t)r*rRS + (size_t)(r>>12)*rBP + rOff + c]);
        if constexpr (RELU)   v = fmaxf(v, 0.f);
        if constexpr (OUTF32) outF[(size_t)r*N + c] = v;
        else                  outH[(size_t)r*N + c] = __float2bfloat16(v);
      }
    }
  }
}

// ---------- LayerNorm over last dim (512), one block per row, bf16 out ----------
template<bool INF32>
__global__ __launch_bounds__(256)
void ln_k(const void* __restrict__ xin, const float* __restrict__ g, const float* __restrict__ bta,
          __hip_bfloat16* __restrict__ outB, int bBP, int bOff)
{
  const int row = blockIdx.x, tid = threadIdx.x;
  float x0, x1;
  if constexpr (INF32){
    const float2 xv = ((const float2*)((const float*)xin + (size_t)row*En))[tid];
    x0 = xv.x; x1 = xv.y;
  } else {
    const unsigned u = ((const unsigned*)((const __hip_bfloat16*)xin + (size_t)row*En))[tid];
    x0 = bfu(u & 0xffffu); x1 = bfu(u >> 16);
  }
  float s = x0 + x1, sq = x0*x0 + x1*x1;
  #pragma unroll
  for (int off=32; off; off>>=1){ s += __shfl_down(s, off); sq += __shfl_down(sq, off); }
  __shared__ float red[8];
  const int w = tid >> 6, lane = tid & 63;
  if (lane == 0){ red[w] = s; red[4+w] = sq; }
  __syncthreads();
  s  = red[0]+red[1]+red[2]+red[3];
  sq = red[4]+red[5]+red[6]+red[7];
  const float mu   = s * (1.f/En);
  const float rstd = rsqrtf(sq * (1.f/En) - mu*mu + 1e-5f);
  const float2 gv = ((const float2*)g)[tid];
  const float2 bv = ((const float2*)bta)[tid];
  const float y0 = (x0 - mu)*rstd*gv.x + bv.x;
  const float y1 = (x1 - mu)*rstd*gv.y + bv.y;
  const size_t base = (size_t)row*En + (size_t)(row>>12)*bBP + bOff + tid*2;
  __hip_bfloat162 o; o.x = __float2bfloat16(y0); o.y = __float2bfloat16(y1);
  *(__hip_bfloat162*)(outB + base) = o;
}

// ---------- linear-space chunked scan over gates packed [row][1536] = f | i | h~ ----------
__global__ __launch_bounds__(256)
void scan_phaseA(const __hip_bfloat16* __restrict__ gi,
                 float* __restrict__ Aagg, float* __restrict__ Bagg)
{
  const int gid = blockIdx.x*256 + threadIdx.x;        // (b, c, hp)  hp in [0,256)
  const int hp = gid & 255, c = (gid >> 8) & 127, b = gid >> 15;
  size_t base = ((size_t)b*Sn + (size_t)c*CHc)*1536 + 2*hp;
  float A0 = 1.f, B0 = 0.f, A1 = 1.f, B1 = 0.f;
  for (int j=0;j<CHc;j++){
    const size_t idx = base + (size_t)j*1536;
    const unsigned uf = *(const unsigned*)(gi + idx);
    const unsigned ui = *(const unsigned*)(gi + idx + 512);
    const unsigned uh = *(const unsigned*)(gi + idx + 1024);
    float fp, ig;
    gate_lin(bfu(uf & 0xffffu), bfu(ui & 0xffffu), bfu(uh & 0xffffu), fp, ig);
    A0 *= fp; B0 = fp*B0 + ig;
    gate_lin(bfu(uf >> 16), bfu(ui >> 16), bfu(uh >> 16), fp, ig);
    A1 *= fp; B1 = fp*B1 + ig;
  }
  const int o = ((b*NCc + c) << 8) + hp;               // float2 index
  ((float2*)Aagg)[o] = make_float2(A0, A1);
  ((float2*)Bagg)[o] = make_float2(B0, B1);
}

__global__ __launch_bounds__(256)
void scan_phaseB(const float* __restrict__ h0, const float* __restrict__ Aagg,
                 const float* __restrict__ Bagg, float* __restrict__ Vst,
                 float* __restrict__ hlast)
{
  const int gid = blockIdx.x*256 + threadIdx.x;        // b*512 + h
  const int h = gid & 511, b = gid >> 9;
  float v = g_of(h0[gid]);
  for (int c=0;c<NCc;c++){
    const int idx = (b*NCc + c)*Hn + h;
    Vst[idx] = v;
    v = fmaf(Aagg[idx], v, Bagg[idx]);
  }
  hlast[gid] = v;
}

__global__ __launch_bounds__(256)
void scan_phaseC(const __hip_bfloat16* __restrict__ gi, const float* __restrict__ Vst,
                 __hip_bfloat16* __restrict__ hseq)
{
  const int gid = blockIdx.x*256 + threadIdx.x;        // (b, c, hp)
  const int hp = gid & 255, c = (gid >> 8) & 127, b = gid >> 15;
  size_t gbase = ((size_t)b*Sn + (size_t)c*CHc)*1536 + 2*hp;
  size_t obase = ((size_t)b*Sn + (size_t)c*CHc)*Hn  + 2*hp;
  const float2 v2 = ((const float2*)Vst)[((b*NCc + c) << 8) + hp];
  float v0 = v2.x, v1 = v2.y;
  for (int j=0;j<CHc;j++){
    const size_t idx = gbase + (size_t)j*1536;
    const unsigned uf = *(const unsigned*)(gi + idx);
    const unsigned ui = *(const unsigned*)(gi + idx + 512);
    const unsigned uh = *(const unsigned*)(gi + idx + 1024);
    float fp, ig;
    gate_lin(bfu(uf & 0xffffu), bfu(ui & 0xffffu), bfu(uh & 0xffffu), fp, ig);
    v0 = fmaf(fp, v0, ig);
    gate_lin(bfu(uf >> 16), bfu(ui >> 16), bfu(uh >> 16), fp, ig);
    v1 = fmaf(fp, v1, ig);
    __hip_bfloat162 o; o.x = __float2bfloat16(v0); o.y = __float2bfloat16(v1);
    *(__hip_bfloat162*)(hseq + obase + (size_t)j*Hn) = o;
  }
}

// ---------- small utility kernels ----------
__global__ void cvt_f32_bf16(const float* __restrict__ src, __hip_bfloat16* __restrict__ dst, int n){
  const int i = blockIdx.x*256 + threadIdx.x;
  if (i < n) dst[i] = __float2bfloat16(src[i]);
}

// conv_w [O=512][I=512][T=4] f32 -> wcv [O][T*512 + I] bf16
__global__ void conv_pack(const float* __restrict__ src, __hip_bfloat16* __restrict__ dst){
  const int d = blockIdx.x*256 + threadIdx.x;
  const int o = d >> 11, r = d & 2047, tap = r >> 9, i = r & 511;
  dst[d] = __float2bfloat16(src[(o*512 + i)*4 + tap]);
}

__global__ void pad_zero(__hip_bfloat16* __restrict__ padded){
  const int gid = blockIdx.x*256 + threadIdx.x;        // 8*3*512
  if (gid < Bn*3*En){
    const int b = gid / (3*En);
    const int j = gid % (3*En);
    const int which = j >> 9, e = j & 511;
    const int u = (which == 0) ? 0 : (4096 + which);   // rows 0, 4097, 4098
    padded[((size_t)b*(Sn+3) + u)*En + e] = __float2bfloat16(0.f);
  }
}

__global__ void pack_bias3(const float* __restrict__ a, const float* __restrict__ b,
                           const float* __restrict__ c, float* __restrict__ dst){
  const int i = blockIdx.x*256 + threadIdx.x;          // 1536
  if (i < 512)       dst[i] = a[i];
  else if (i < 1024) dst[i] = b[i-512];
  else if (i < 1536) dst[i] = c[i-1024];
}

extern "C" void kernel_launch(void* const* d_in, const int* in_sizes, int n_in,
                              void* d_out, int out_size, void* d_ws, size_t ws_size,
                              hipStream_t stream)
{
  const float* x     = (const float*)d_in[0];
  const float* h0    = (const float*)d_in[1];
  const float* lf_w  = (const float*)d_in[2];
  const float* lf_b  = (const float*)d_in[3];
  const float* li_w  = (const float*)d_in[4];
  const float* li_b  = (const float*)d_in[5];
  const float* lh_w  = (const float*)d_in[6];
  const float* lh_b  = (const float*)d_in[7];
  const float* out_w = (const float*)d_in[8];
  const float* out_b = (const float*)d_in[9];
  const float* conv_w= (const float*)d_in[10];
  const float* conv_b= (const float*)d_in[11];
  const float* ln_g  = (const float*)d_in[12];
  const float* ln_b  = (const float*)d_in[13];
  const float* w1    = (const float*)d_in[14];
  const float* b1    = (const float*)d_in[15];
  const float* w2    = (const float*)d_in[16];
  const float* b2    = (const float*)d_in[17];

  float* outx = (float*)d_out;
  float* outh = outx + (size_t)Mn*En;

  // ---- workspace layout (overlay plan) ----
  const size_t AGG = (size_t)Bn*NCc*Hn*4;              // 2 MB each
  const size_t NEED = 5*SLOT + 3*AGG + 8388608 + 6144;
  if (ws_size < NEED) return;

  char* W = (char*)d_ws;
  __hip_bfloat16* GI   = (__hip_bfloat16*)(W);
  __hip_bfloat16* X2   = (__hip_bfloat16*)(W);
  __hip_bfloat16* G1   = (__hip_bfloat16*)(W + SLOT);
  __hip_bfloat16* X3   = (__hip_bfloat16*)(W + 2*SLOT);
  __hip_bfloat16* HSEQ = (__hip_bfloat16*)(W + 3*SLOT);
  __hip_bfloat16* hmid = (__hip_bfloat16*)(W);
  __hip_bfloat16* XN1  = (__hip_bfloat16*)(W + 4*SLOT);   // later XN3
  float* Aagg = (float*)(W + 5*SLOT);
  float* Bagg = Aagg + (size_t)Bn*NCc*Hn;
  float* Vst  = Bagg + (size_t)Bn*NCc*Hn;
  __hip_bfloat16* wg3  = (__hip_bfloat16*)(Vst + (size_t)Bn*NCc*Hn);
  __hip_bfloat16* wout = wg3  + 1536*512;
  __hip_bfloat16* wcv  = wout + 512*512;
  __hip_bfloat16* wm1  = wcv  + 512*2048;
  __hip_bfloat16* wm2  = wm1  + 2048*512;
  float* bg3 = (float*)(wm2 + 512*2048);

  // weight prep
  cvt_f32_bf16<<<1024, 256, 0, stream>>>(lf_w, wg3,            512*512);
  cvt_f32_bf16<<<1024, 256, 0, stream>>>(li_w, wg3 +  512*512, 512*512);
  cvt_f32_bf16<<<1024, 256, 0, stream>>>(lh_w, wg3 + 1024*512, 512*512);
  cvt_f32_bf16<<<1024, 256, 0, stream>>>(out_w, wout, 512*512);
  cvt_f32_bf16<<<4096, 256, 0, stream>>>(w1, wm1, 2048*512);
  cvt_f32_bf16<<<4096, 256, 0, stream>>>(w2, wm2, 512*2048);
  conv_pack   <<<4096, 256, 0, stream>>>(conv_w, wcv);
  pack_bias3  <<<6,    256, 0, stream>>>(lf_b, li_b, lh_b, bg3);

  // LN1: x(f32) -> XN1 bf16
  ln_k<true><<<Mn, 256, 0, stream>>>(x, ln_g, ln_b, XN1, 0, 0);

  // fused gate GEMM: [Mn,512] x [1536,512]^T -> GI [Mn,1536]   (128 x 6 tiles)
  gemm_bf16<0,false,false><<<768, 512, 0, stream>>>(XN1, wg3, 1536, 512, 512, 0, bg3, nullptr, 0,0,0, GI);

  // linear-space chunked scan -> HSEQ bf16, h_last f32
  scan_phaseA<<<1024, 256, 0, stream>>>(GI, Aagg, Bagg);
  scan_phaseB<<<16,   256, 0, stream>>>(h0, Aagg, Bagg, Vst, outh);
  scan_phaseC<<<1024, 256, 0, stream>>>(GI, Vst, HSEQ);

  // zero pad rows of G1 (after GI is dead — G1 overlays S1)
  pad_zero<<<48, 256, 0, stream>>>(G1);

  // out-proj + residual(XN1) -> X2 bf16   (128 x 2 tiles)
  gemm_bf16<1,false,false><<<256, 512, 0, stream>>>(HSEQ, wout, 512, 512, 512, 0, out_b, XN1, 512, 0, 0, X2);

  // LN2: X2 -> padded G1 (row t -> padded row t+1)
  ln_k<false><<<Mn, 256, 0, stream>>>(X2, ln_g, ln_b, G1, 3*En, En);

  // conv as K=2048 GEMM over padded rows + residual(xn2 from G1) -> X3 bf16
  gemm_bf16<1,false,false><<<256, 512, 0, stream>>>(G1, wcv, 512, 2048, 512, 3*En, conv_b, G1, 512, 3*En, En, X3);

  // LN3: X3 -> XN3 bf16 (reuses XN1 slot)
  ln_k<false><<<Mn, 256, 0, stream>>>(X3, ln_g, ln_b, XN1, 0, 0);

  // MLP: relu(XN3 @ w1^T) -> hmid (128 x 8 tiles);  hmid @ w2^T + XN3 -> outx (f32)
  gemm_bf16<0,true ,false><<<1024, 512, 0, stream>>>(XN1, wm1, 2048, 512, 512, 0, b1, nullptr, 0,0,0, hmid);
  gemm_bf16<1,false,true ><<<256,  512, 0, stream>>>(hmid, wm2, 512, 2048, 2048, 0, b2, XN1, 512, 0, 0, outx);
}

// Round 14
// 506.769 us; speedup vs baseline: 1.3102x; 1.1277x over previous
//
#include <hip/hip_runtime.h>
#include <hip/hip_bf16.h>

typedef __attribute__((ext_vector_type(8))) short bf16x8v;
typedef __attribute__((ext_vector_type(4))) float f32x4v;

#define DEV __device__ __forceinline__

constexpr int Bn = 8, Sn = 4096, En = 512, Hn = 512;
constexpr int Mn = Bn * Sn;          // 32768 rows
constexpr int NCc = 128, CHc = 32;   // scan: 128 chunks of 32
constexpr size_t SLOT = 33579008;    // = 8*4099*512*2 bytes (padded-conv buffer), 4096-aligned

// ---------- math helpers ----------
DEV float bfu(unsigned u){ union{unsigned v; float f;} c; c.v = u << 16; return c.f; }

DEV void gload16(const void* g, void* l){
  __builtin_amdgcn_global_load_lds((const __attribute__((address_space(1))) void*)g,
                                   (__attribute__((address_space(3))) void*)l, 16, 0, 0);
}

// linear-space gates: f' = (1+e^-i)/(2+e^-f+e^-i), i' = (1+e^-f)/(...), g = x>=0? x+.5 : sigmoid(x)
DEV void gate_lin(float f, float i, float hp, float& fp, float& ig){
  const float ef = __expf(-f);
  const float ei = __expf(-i);
  const float rd = 1.f / (2.f + ef + ei);
  fp = (1.f + ei) * rd;
  const float ipv = (1.f + ef) * rd;
  const float g = (hp >= 0.f) ? (hp + 0.5f) : (1.f / (1.f + __expf(-hp)));
  ig = ipv * g;
}

DEV float g_of(float x){ return (x >= 0.f) ? (x + 0.5f) : (1.f / (1.f + __expf(-x))); }

// ---------- bf16 MFMA GEMM, 256x256 tile, BK=64, 8 waves (2Mx4N), 512 thr ----------
// r13's 8-phase counted-vmcnt schedule, with the STAGING ADDRESS PATTERN fixed:
// old mapping put consecutive lanes on consecutive ROWS (1KB apart) -> every
// gload_lds = 64 distinct cache-line requests; ~1024 line-requests/phase/block
// saturated the CU request path (~1/cy) = the measured 1555cy/phase residue that
// made every schedule variant null.
// New mapping: slot s -> row=s>>2, chunk=s&3 (4 lanes cover one row's 64B line)
// = 16 lines/instr (4x fewer requests). LDS is linear [Kh][row][32k] with the
// involutive chunk-XOR c' = c ^ ((row>>1)&3) applied BOTH on the pre-swizzled
// global source (write side) and on the ds_read address (read side) (rule #21).
// Read-bank audit: 16 lanes = (row&1)x2 groups x 4 XOR positions = 32 banks at
// 2-way aliasing = free (m136). Content check: read c'=kc^xk -> global chunk kc.
// C[M,N] = A(row-mapped)[M,K] * Bw[N,K]^T + bias
// RES: 0 none, 1 add bf16 residual at res[r*rRS + (r>>12)*rBP + rOff + c]
template<int RES, bool RELU, bool OUTF32>
__global__ __launch_bounds__(512, 1)
void gemm_bf16(const __hip_bfloat16* __restrict__ A,
               const __hip_bfloat16* __restrict__ Bw,
               int N, int K, int aRS, int aBP,
               const float* __restrict__ bias,
               const __hip_bfloat16* __restrict__ res, int rRS, int rBP, int rOff,
               void* __restrict__ out)
{
  __shared__ __align__(16) __hip_bfloat16 Al[2][2][256][32];   // [buf][Kh][row][k] 64 KB
  __shared__ __align__(16) __hip_bfloat16 Bl[2][2][256][32];   // 64 KB
  const int tid  = threadIdx.x;
  const int lane = tid & 63;
  const int w    = tid >> 6;            // 0..7
  const int ntn  = N >> 8;
  // T1: XCD-aware bijective swizzle (all grids are multiples of 8)
  const int nwg = gridDim.x;
  int wg = blockIdx.x;
  if ((nwg & 7) == 0) wg = ((wg & 7) * (nwg >> 3)) + (wg >> 3);
  const int bm = wg / ntn, bn = wg % ntn;
  const int rowBase = bm << 8, colBase = bn << 8;
  const int wm = w >> 2, wn = w & 3;    // 2 x 4 wave grid
  const int r0 = lane & 15, kc = lane >> 4;
  const int xk = (r0 >> 1) & 3;         // read-side XOR key (row bits 1..2 = r0 bits 1..2)
  const int rc = (kc ^ xk) << 3;        // element offset of fragment within [32k] row

  f32x4v acc[8][4];
  #pragma unroll
  for (int i=0;i<8;i++)
    #pragma unroll
    for (int j=0;j<4;j++)
      #pragma unroll
      for (int q=0;q<4;q++) acc[i][j][q] = 0.f;

  // staging slots: s=(j<<9)+tid; row=s>>2 (0..255), cp=s&3, src chunk = cp^((row>>1)&3)
  // -> 4 consecutive lanes read one row's 64B line (permuted within = still 1 line)
  int sr[2], scp[2];
  size_t aoff[2], boff[2];
  #pragma unroll
  for (int j=0;j<2;j++){
    const int s  = (j<<9) + tid;        // 0..1023
    const int r  = s >> 2;
    const int cp = s & 3;
    const int cs = cp ^ ((r >> 1) & 3);
    sr[j] = r; scp[j] = cp;
    const int rowg = rowBase + r;
    aoff[j] = (size_t)rowg*aRS + (size_t)(rowg>>12)*aBP + (cs<<3);
    boff[j] = (size_t)(colBase + r)*K + (cs<<3);
  }

  // unit: 0=A-K0, 1=B-K0, 2=A-K1, 3=B-K1  (issue order matters for vmcnt math)
  auto stage_unit = [&](int buf, int unit, int t){
    const int Kh = unit >> 1;
    const int ke = (t<<6) + (Kh<<5);
    if ((unit & 1) == 0){
      #pragma unroll
      for (int j=0;j<2;j++) gload16(A  + aoff[j] + ke, &Al[buf][Kh][sr[j]][scp[j]<<3]);
    } else {
      #pragma unroll
      for (int j=0;j<2;j++) gload16(Bw + boff[j] + ke, &Bl[buf][Kh][sr[j]][scp[j]<<3]);
    }
  };

  const int NT = K >> 6;           // 8 (K=512) or 32 (K=2048)

  // prologue: stage all 4 units of tile 0; first 2 units (K0) must land
  stage_unit(0,0,0); stage_unit(0,1,0); stage_unit(0,2,0); stage_unit(0,3,0);
  asm volatile("s_waitcnt vmcnt(4)" ::: "memory");
  __builtin_amdgcn_s_barrier();

  bf16x8v bfv[4];
  for (int t=0; t<NT; t++){
    const int cur = t & 1, nxt = cur ^ 1;
    const bool pre = (t+1 < NT);
    #pragma unroll
    for (int ph=0; ph<4; ph++){
      const int h = ph & 1, kk = ph >> 1;
      // ds-read this phase's fragments (XOR-swizzled chunk; compiler handles lgkm)
      bf16x8v af[4];
      if (h == 0){
        #pragma unroll
        for (int ni=0;ni<4;ni++) bfv[ni] = *(const bf16x8v*)&Bl[cur][kk][(wn<<6)+(ni<<4)+r0][rc];
      }
      #pragma unroll
      for (int m=0;m<4;m++) af[m] = *(const bf16x8v*)&Al[cur][kk][(wm<<7)+(((h<<2)+m)<<4)+r0][rc];
      // stage one unit of tile t+1
      if (pre) stage_unit(nxt, ph, t+1);
      // counted waits: protect staged data of LATER phases (never 0 mid-loop)
      if (ph == 1 || ph == 3){
        if (pre) asm volatile("s_waitcnt vmcnt(4)" ::: "memory");
        else     asm volatile("s_waitcnt vmcnt(0)" ::: "memory");
      }
      __builtin_amdgcn_s_barrier();
      __builtin_amdgcn_s_setprio(1);
      #pragma unroll
      for (int m=0;m<4;m++)
        #pragma unroll
        for (int ni=0;ni<4;ni++)
          acc[(h<<2)+m][ni] = __builtin_amdgcn_mfma_f32_16x16x32_bf16(af[m], bfv[ni], acc[(h<<2)+m][ni], 0, 0, 0);
      __builtin_amdgcn_s_setprio(0);
      __builtin_amdgcn_s_barrier();
    }
  }

  float* outF = (float*)out;
  __hip_bfloat16* outH = (__hip_bfloat16*)out;
  const int q = lane >> 4;
  float bia[4];
  #pragma unroll
  for (int ni=0;ni<4;ni++) bia[ni] = bias[colBase + (wn<<6) + (ni<<4) + r0];
  #pragma unroll
  for (int mi=0;mi<8;mi++){
    const int rb = rowBase + (wm<<7) + (mi<<4) + (q<<2);
    #pragma unroll
    for (int j=0;j<4;j++){
      const int r = rb + j;
      #pragma unroll
      for (int ni=0;ni<4;ni++){        // ni innermost: adjacent 32B chunks per row
        const int c = colBase + (wn<<6) + (ni<<4) + r0;
        float v = acc[mi][ni][j] + bia[ni];
        if constexpr (RES==1) v += __bfloat162float(res[(size_t)r*rRS + (size_t)(r>>12)*rBP + rOff + c]);
        if constexpr (RELU)   v = fmaxf(v, 0.f);
        if constexpr (OUTF32) outF[(size_t)r*N + c] = v;
        else                  outH[(size_t)r*N + c] = __float2bfloat16(v);
      }
    }
  }
}

// ---------- LayerNorm over last dim (512), one block per row, bf16 out ----------
template<bool INF32>
__global__ __launch_bounds__(256)
void ln_k(const void* __restrict__ xin, const float* __restrict__ g, const float* __restrict__ bta,
          __hip_bfloat16* __restrict__ outB, int bBP, int bOff)
{
  const int row = blockIdx.x, tid = threadIdx.x;
  float x0, x1;
  if constexpr (INF32){
    const float2 xv = ((const float2*)((const float*)xin + (size_t)row*En))[tid];
    x0 = xv.x; x1 = xv.y;
  } else {
    const unsigned u = ((const unsigned*)((const __hip_bfloat16*)xin + (size_t)row*En))[tid];
    x0 = bfu(u & 0xffffu); x1 = bfu(u >> 16);
  }
  float s = x0 + x1, sq = x0*x0 + x1*x1;
  #pragma unroll
  for (int off=32; off; off>>=1){ s += __shfl_down(s, off); sq += __shfl_down(sq, off); }
  __shared__ float red[8];
  const int w = tid >> 6, lane = tid & 63;
  if (lane == 0){ red[w] = s; red[4+w] = sq; }
  __syncthreads();
  s  = red[0]+red[1]+red[2]+red[3];
  sq = red[4]+red[5]+red[6]+red[7];
  const float mu   = s * (1.f/En);
  const float rstd = rsqrtf(sq * (1.f/En) - mu*mu + 1e-5f);
  const float2 gv = ((const float2*)g)[tid];
  const float2 bv = ((const float2*)bta)[tid];
  const float y0 = (x0 - mu)*rstd*gv.x + bv.x;
  const float y1 = (x1 - mu)*rstd*gv.y + bv.y;
  const size_t base = (size_t)row*En + (size_t)(row>>12)*bBP + bOff + tid*2;
  __hip_bfloat162 o; o.x = __float2bfloat16(y0); o.y = __float2bfloat16(y1);
  *(__hip_bfloat162*)(outB + base) = o;
}

// ---------- linear-space chunked scan over gates packed [row][1536] = f | i | h~ ----------
__global__ __launch_bounds__(256)
void scan_phaseA(const __hip_bfloat16* __restrict__ gi,
                 float* __restrict__ Aagg, float* __restrict__ Bagg)
{
  const int gid = blockIdx.x*256 + threadIdx.x;        // (b, c, hp)  hp in [0,256)
  const int hp = gid & 255, c = (gid >> 8) & 127, b = gid >> 15;
  size_t base = ((size_t)b*Sn + (size_t)c*CHc)*1536 + 2*hp;
  float A0 = 1.f, B0 = 0.f, A1 = 1.f, B1 = 0.f;
  for (int j=0;j<CHc;j++){
    const size_t idx = base + (size_t)j*1536;
    const unsigned uf = *(const unsigned*)(gi + idx);
    const unsigned ui = *(const unsigned*)(gi + idx + 512);
    const unsigned uh = *(const unsigned*)(gi + idx + 1024);
    float fp, ig;
    gate_lin(bfu(uf & 0xffffu), bfu(ui & 0xffffu), bfu(uh & 0xffffu), fp, ig);
    A0 *= fp; B0 = fp*B0 + ig;
    gate_lin(bfu(uf >> 16), bfu(ui >> 16), bfu(uh >> 16), fp, ig);
    A1 *= fp; B1 = fp*B1 + ig;
  }
  const int o = ((b*NCc + c) << 8) + hp;               // float2 index
  ((float2*)Aagg)[o] = make_float2(A0, A1);
  ((float2*)Bagg)[o] = make_float2(B0, B1);
}

__global__ __launch_bounds__(256)
void scan_phaseB(const float* __restrict__ h0, const float* __restrict__ Aagg,
                 const float* __restrict__ Bagg, float* __restrict__ Vst,
                 float* __restrict__ hlast)
{
  const int gid = blockIdx.x*256 + threadIdx.x;        // b*512 + h
  const int h = gid & 511, b = gid >> 9;
  float v = g_of(h0[gid]);
  for (int c=0;c<NCc;c++){
    const int idx = (b*NCc + c)*Hn + h;
    Vst[idx] = v;
    v = fmaf(Aagg[idx], v, Bagg[idx]);
  }
  hlast[gid] = v;
}

__global__ __launch_bounds__(256)
void scan_phaseC(const __hip_bfloat16* __restrict__ gi, const float* __restrict__ Vst,
                 __hip_bfloat16* __restrict__ hseq)
{
  const int gid = blockIdx.x*256 + threadIdx.x;        // (b, c, hp)
  const int hp = gid & 255, c = (gid >> 8) & 127, b = gid >> 15;
  size_t gbase = ((size_t)b*Sn + (size_t)c*CHc)*1536 + 2*hp;
  size_t obase = ((size_t)b*Sn + (size_t)c*CHc)*Hn  + 2*hp;
  const float2 v2 = ((const float2*)Vst)[((b*NCc + c) << 8) + hp];
  float v0 = v2.x, v1 = v2.y;
  for (int j=0;j<CHc;j++){
    const size_t idx = gbase + (size_t)j*1536;
    const unsigned uf = *(const unsigned*)(gi + idx);
    const unsigned ui = *(const unsigned*)(gi + idx + 512);
    const unsigned uh = *(const unsigned*)(gi + idx + 1024);
    float fp, ig;
    gate_lin(bfu(uf & 0xffffu), bfu(ui & 0xffffu), bfu(uh & 0xffffu), fp, ig);
    v0 = fmaf(fp, v0, ig);
    gate_lin(bfu(uf >> 16), bfu(ui >> 16), bfu(uh >> 16), fp, ig);
    v1 = fmaf(fp, v1, ig);
    __hip_bfloat162 o; o.x = __float2bfloat16(v0); o.y = __float2bfloat16(v1);
    *(__hip_bfloat162*)(hseq + obase + (size_t)j*Hn) = o;
  }
}

// ---------- small utility kernels ----------
__global__ void cvt_f32_bf16(const float* __restrict__ src, __hip_bfloat16* __restrict__ dst, int n){
  const int i = blockIdx.x*256 + threadIdx.x;
  if (i < n) dst[i] = __float2bfloat16(src[i]);
}

// conv_w [O=512][I=512][T=4] f32 -> wcv [O][T*512 + I] bf16
__global__ void conv_pack(const float* __restrict__ src, __hip_bfloat16* __restrict__ dst){
  const int d = blockIdx.x*256 + threadIdx.x;
  const int o = d >> 11, r = d & 2047, tap = r >> 9, i = r & 511;
  dst[d] = __float2bfloat16(src[(o*512 + i)*4 + tap]);
}

__global__ void pad_zero(__hip_bfloat16* __restrict__ padded){
  const int gid = blockIdx.x*256 + threadIdx.x;        // 8*3*512
  if (gid < Bn*3*En){
    const int b = gid / (3*En);
    const int j = gid % (3*En);
    const int which = j >> 9, e = j & 511;
    const int u = (which == 0) ? 0 : (4096 + which);   // rows 0, 4097, 4098
    padded[((size_t)b*(Sn+3) + u)*En + e] = __float2bfloat16(0.f);
  }
}

__global__ void pack_bias3(const float* __restrict__ a, const float* __restrict__ b,
                           const float* __restrict__ c, float* __restrict__ dst){
  const int i = blockIdx.x*256 + threadIdx.x;          // 1536
  if (i < 512)       dst[i] = a[i];
  else if (i < 1024) dst[i] = b[i-512];
  else if (i < 1536) dst[i] = c[i-1024];
}

extern "C" void kernel_launch(void* const* d_in, const int* in_sizes, int n_in,
                              void* d_out, int out_size, void* d_ws, size_t ws_size,
                              hipStream_t stream)
{
  const float* x     = (const float*)d_in[0];
  const float* h0    = (const float*)d_in[1];
  const float* lf_w  = (const float*)d_in[2];
  const float* lf_b  = (const float*)d_in[3];
  const float* li_w  = (const float*)d_in[4];
  const float* li_b  = (const float*)d_in[5];
  const float* lh_w  = (const float*)d_in[6];
  const float* lh_b  = (const float*)d_in[7];
  const float* out_w = (const float*)d_in[8];
  const float* out_b = (const float*)d_in[9];
  const float* conv_w= (const float*)d_in[10];
  const float* conv_b= (const float*)d_in[11];
  const float* ln_g  = (const float*)d_in[12];
  const float* ln_b  = (const float*)d_in[13];
  const float* w1    = (const float*)d_in[14];
  const float* b1    = (const float*)d_in[15];
  const float* w2    = (const float*)d_in[16];
  const float* b2    = (const float*)d_in[17];

  float* outx = (float*)d_out;
  float* outh = outx + (size_t)Mn*En;

  // ---- workspace layout (overlay plan) ----
  const size_t AGG = (size_t)Bn*NCc*Hn*4;              // 2 MB each
  const size_t NEED = 5*SLOT + 3*AGG + 8388608 + 6144;
  if (ws_size < NEED) return;

  char* W = (char*)d_ws;
  __hip_bfloat16* GI   = (__hip_bfloat16*)(W);
  __hip_bfloat16* X2   = (__hip_bfloat16*)(W);
  __hip_bfloat16* G1   = (__hip_bfloat16*)(W + SLOT);
  __hip_bfloat16* X3   = (__hip_bfloat16*)(W + 2*SLOT);
  __hip_bfloat16* HSEQ = (__hip_bfloat16*)(W + 3*SLOT);
  __hip_bfloat16* hmid = (__hip_bfloat16*)(W);
  __hip_bfloat16* XN1  = (__hip_bfloat16*)(W + 4*SLOT);   // later XN3
  float* Aagg = (float*)(W + 5*SLOT);
  float* Bagg = Aagg + (size_t)Bn*NCc*Hn;
  float* Vst  = Bagg + (size_t)Bn*NCc*Hn;
  __hip_bfloat16* wg3  = (__hip_bfloat16*)(Vst + (size_t)Bn*NCc*Hn);
  __hip_bfloat16* wout = wg3  + 1536*512;
  __hip_bfloat16* wcv  = wout + 512*512;
  __hip_bfloat16* wm1  = wcv  + 512*2048;
  __hip_bfloat16* wm2  = wm1  + 2048*512;
  float* bg3 = (float*)(wm2 + 512*2048);

  // weight prep
  cvt_f32_bf16<<<1024, 256, 0, stream>>>(lf_w, wg3,            512*512);
  cvt_f32_bf16<<<1024, 256, 0, stream>>>(li_w, wg3 +  512*512, 512*512);
  cvt_f32_bf16<<<1024, 256, 0, stream>>>(lh_w, wg3 + 1024*512, 512*512);
  cvt_f32_bf16<<<1024, 256, 0, stream>>>(out_w, wout, 512*512);
  cvt_f32_bf16<<<4096, 256, 0, stream>>>(w1, wm1, 2048*512);
  cvt_f32_bf16<<<4096, 256, 0, stream>>>(w2, wm2, 512*2048);
  conv_pack   <<<4096, 256, 0, stream>>>(conv_w, wcv);
  pack_bias3  <<<6,    256, 0, stream>>>(lf_b, li_b, lh_b, bg3);

  // LN1: x(f32) -> XN1 bf16
  ln_k<true><<<Mn, 256, 0, stream>>>(x, ln_g, ln_b, XN1, 0, 0);

  // fused gate GEMM: [Mn,512] x [1536,512]^T -> GI [Mn,1536]   (128 x 6 tiles)
  gemm_bf16<0,false,false><<<768, 512, 0, stream>>>(XN1, wg3, 1536, 512, 512, 0, bg3, nullptr, 0,0,0, GI);

  // linear-space chunked scan -> HSEQ bf16, h_last f32
  scan_phaseA<<<1024, 256, 0, stream>>>(GI, Aagg, Bagg);
  scan_phaseB<<<16,   256, 0, stream>>>(h0, Aagg, Bagg, Vst, outh);
  scan_phaseC<<<1024, 256, 0, stream>>>(GI, Vst, HSEQ);

  // zero pad rows of G1 (after GI is dead — G1 overlays S1)
  pad_zero<<<48, 256, 0, stream>>>(G1);

  // out-proj + residual(XN1) -> X2 bf16   (128 x 2 tiles)
  gemm_bf16<1,false,false><<<256, 512, 0, stream>>>(HSEQ, wout, 512, 512, 512, 0, out_b, XN1, 512, 0, 0, X2);

  // LN2: X2 -> padded G1 (row t -> padded row t+1)
  ln_k<false><<<Mn, 256, 0, stream>>>(X2, ln_g, ln_b, G1, 3*En, En);

  // conv as K=2048 GEMM over padded rows + residual(xn2 from G1) -> X3 bf16
  gemm_bf16<1,false,false><<<256, 512, 0, stream>>>(G1, wcv, 512, 2048, 512, 3*En, conv_b, G1, 512, 3*En, En, X3);

  // LN3: X3 -> XN3 bf16 (reuses XN1 slot)
  ln_k<false><<<Mn, 256, 0, stream>>>(X3, ln_g, ln_b, XN1, 0, 0);

  // MLP: relu(XN3 @ w1^T) -> hmid (128 x 8 tiles);  hmid @ w2^T + XN3 -> outx (f32)
  gemm_bf16<0,true ,false><<<1024, 512, 0, stream>>>(XN1, wm1, 2048, 512, 512, 0, b1, nullptr, 0,0,0, hmid);
  gemm_bf16<1,false,true ><<<256,  512, 0, stream>>>(hmid, wm2, 512, 2048, 2048, 0, b2, XN1, 512, 0, 0, outx);
}